// Round 2
// baseline (563.297 us; speedup 1.0000x reference)
//
#include <hip/hip_runtime.h>
#include <stdint.h>

#define NA 10
#define DIM 512
#define LIN_SCALE 0.08838834764831845f   // 1/sqrt(128)
#define TP_SCALE  0.027950849718747374f  // 1/sqrt(1280)

#define PLANE_SZ 655360   // 10a * 8c * 8nb * 64lane * 16B
#define CHUNK_SZ 8192     // 8nb * 64lane * 16B

typedef __attribute__((ext_vector_type(8))) short short8;
typedef __attribute__((ext_vector_type(8))) __bf16 bf16x8;
typedef __attribute__((ext_vector_type(4))) float f32x4;
typedef __attribute__((ext_vector_type(4))) float float4v;

static __device__ __forceinline__ unsigned short f2bf(float x) {
  unsigned int u = __float_as_uint(x);
  u += 0x7fffu + ((u >> 16) & 1u);
  return (unsigned short)(u >> 16);
}
static __device__ __forceinline__ float bf2f(unsigned short h) {
  return __uint_as_float(((unsigned int)h) << 16);
}

#define MFMA_BF16(A, B, C) __builtin_amdgcn_mfma_f32_16x16x32_bf16( \
    __builtin_bit_cast(bf16x8, (A)), __builtin_bit_cast(bf16x8, (B)), (C), 0, 0, 0)

// ---------------- bucketing ----------------
// ws int layout: [0..15] cnt, [16..31] offs, [32..47] cursor, [64..] idx[N]
__global__ void k_zero(int* wsI) {
  if (threadIdx.x < 48) wsI[threadIdx.x] = 0;
}

__global__ __launch_bounds__(256) void k_count(const float* __restrict__ attrs,
                                               int* wsI, int N) {
  __shared__ int h[16];
  int t = threadIdx.x;
  int n = blockIdx.x * 256 + t;
  if (t < 16) h[t] = 0;
  __syncthreads();
  if (n < N) {
    int a = 0;
    #pragma unroll
    for (int j = 1; j < NA; ++j) if (attrs[n * NA + j] > 0.5f) a = j;
    atomicAdd(&h[a], 1);
  }
  __syncthreads();
  if (t < NA && h[t] > 0) atomicAdd(&wsI[t], h[t]);
}

__global__ void k_scan(int* wsI) {
  if (threadIdx.x == 0) {
    int run = 0;
    for (int a = 0; a < NA; ++a) {
      wsI[16 + a] = run;
      wsI[32 + a] = run;
      run += wsI[a];
    }
  }
}

__global__ __launch_bounds__(256) void k_scatter(const float* __restrict__ attrs,
                                                 int* wsI, int N) {
  __shared__ int h[16], base[16], c2[16];
  int t = threadIdx.x;
  int n = blockIdx.x * 256 + t;
  if (t < 16) { h[t] = 0; c2[t] = 0; }
  __syncthreads();
  int a = 0;
  if (n < N) {
    #pragma unroll
    for (int j = 1; j < NA; ++j) if (attrs[n * NA + j] > 0.5f) a = j;
    atomicAdd(&h[a], 1);
  }
  __syncthreads();
  if (t < NA && h[t] > 0) base[t] = atomicAdd(&wsI[32 + t], h[t]);
  __syncthreads();
  if (n < N) {
    int r = atomicAdd(&c2[a], 1);
    wsI[64 + base[a] + r] = n;
  }
}

// ---------------- weight prep: pack scale-folded bf16 hi/lo MFMA fragments ----------------
// wb layout: plane0 = Bs_hi, plane1 = Bs_lo, plane2 = Bv_hi, plane3 = Bv_lo (each PLANE_SZ)
// within plane: [a][c][nb][lane][8 bf16]   (c = k-chunk of 32, K=256 stacked [Wl;Wt_a])
__global__ __launch_bounds__(256) void k_prep(const float* __restrict__ Wl0,
                                              const float* __restrict__ Wl1,
                                              const float* __restrict__ Wt0,
                                              const float* __restrict__ Wt1,
                                              char* __restrict__ wb) {
  int gid = blockIdx.x * 256 + threadIdx.x;  // 0..81919 = 2type*10a*8c*8nb*64lane
  int l  = gid & 63;
  int nb = (gid >> 6) & 7;
  int c  = (gid >> 9) & 7;
  int ac = gid >> 12;        // 0..19
  int a  = ac % NA;
  int type = ac / NA;
  const float* Wl = type ? Wl1 : Wl0;
  const float* Wt = type ? Wt1 : Wt0;
  char* bh = wb + (size_t)type * (2 * (size_t)PLANE_SZ);
  char* bl = bh + PLANE_SZ;
  size_t slot = ((size_t)((a * 8 + c) * 8 + nb) * 64 + l) * 16;
  short8 h8, l8;
  #pragma unroll
  for (int e = 0; e < 8; ++e) {
    // A/B fragment k-mapping for mfma_f32_16x16x32_bf16:
    // k = (lane>>4)*4 + (e&3) + (e>>2)*16 ; col = lane&15
    int k = c * 32 + (e >> 2) * 16 + (l >> 4) * 4 + (e & 3);
    int n = nb * 16 + (l & 15);
    float w = (k < 128) ? (LIN_SCALE * Wl[k * 128 + n])
                        : (TP_SCALE * Wt[(size_t)(k - 128) * (NA * 128) + a * 128 + n]);
    unsigned short hb = f2bf(w);
    h8[e] = (short)hb;
    l8[e] = (short)f2bf(w - bf2f(hb));
  }
  *(short8*)(bh + slot) = h8;
  *(short8*)(bl + slot) = l8;
}

// ---------------- main GEMM ----------------
// block: 64 nodes of one bucket, 256 threads (4 waves).
// A tile rb 0..3 = scalar rows, rb 4+4x.. = vector channel x rows.
// B fragments read straight from prepacked ws (L2-resident, no LDS).
// LDS = Ah(16K)+Al(16K)+nidx(256B) = 32.25KB  (fits; previous rev overflowed 64KB)
__global__ __launch_bounds__(256, 2) void k_gemm(const float* __restrict__ m_i,
                                                 const float* __restrict__ feats,
                                                 const int* __restrict__ wsI,
                                                 const char* __restrict__ wb,
                                                 float* __restrict__ out) {
  __shared__ __attribute__((aligned(16))) short Ah[16][64][8];
  __shared__ __attribute__((aligned(16))) short Al[16][64][8];
  __shared__ int nidx[64];

  const int a  = blockIdx.y;
  const int t0 = blockIdx.x * 64;
  const int ca = wsI[a];
  if (t0 >= ca) return;
  const int nn = (ca - t0 < 64) ? (ca - t0) : 64;
  const int tid = threadIdx.x;
  if (tid < 64) nidx[tid] = (tid < nn) ? wsI[64 + wsI[16 + a] + t0 + tid] : 0;

  const int wid  = tid >> 6;
  const int lane = tid & 63;
  const int nd   = tid >> 2;   // staging: node 0..63
  const int w    = tid & 3;    // staging: k-quad slot 0..3

  // B plane base for this wave (wave0: scalar planes 0/1, waves1-3: vector planes 2/3)
  const char* bp_h = wb + (size_t)(wid ? 2 : 0) * PLANE_SZ + (size_t)a * (8 * CHUNK_SZ);
  const char* bp_l = bp_h + PLANE_SZ;

  f32x4 acc[4][8];
  #pragma unroll
  for (int i = 0; i < 4; ++i)
    #pragma unroll
    for (int nbv = 0; nbv < 8; ++nbv)
      acc[i][nbv] = (f32x4){0.f, 0.f, 0.f, 0.f};

  for (int c = 0; c < 8; ++c) {
    __syncthreads();
    // ---- stage A: gather node rows, split fp32 -> bf16 hi/lo fragments ----
    {
      const float* src = (c < 4) ? m_i : feats;
      const int cc = c & 3;
      const float* row = src + (size_t)nidx[nd] * DIM;
      const bool ok = (nd < nn);
      // scalar rows: cols [32cc, 32cc+32)
      {
        float4v f0 = {0,0,0,0}, f1 = {0,0,0,0};
        if (ok) {
          f0 = *(const float4v*)(row + cc * 32 + 4 * w);
          f1 = *(const float4v*)(row + cc * 32 + 16 + 4 * w);
        }
        short8 h8, l8;
        #pragma unroll
        for (int j = 0; j < 4; ++j) {
          unsigned short hb = f2bf(f0[j]);
          h8[j] = (short)hb; l8[j] = (short)f2bf(f0[j] - bf2f(hb));
          unsigned short hb2 = f2bf(f1[j]);
          h8[4 + j] = (short)hb2; l8[4 + j] = (short)f2bf(f1[j] - bf2f(hb2));
        }
        const int rb = nd >> 4, ln = (nd & 15) + 16 * w;
        *(short8*)&Ah[rb][ln][0] = h8;
        *(short8*)&Al[rb][ln][0] = l8;
      }
      // vector rows: interleaved cols 128 + 3*k + x, two 12-float runs
      {
        const int vb = 128 + cc * 96 + 12 * w;
        float4v g[6];
        #pragma unroll
        for (int q = 0; q < 6; ++q) g[q] = (float4v){0,0,0,0};
        if (ok) {
          g[0] = *(const float4v*)(row + vb);
          g[1] = *(const float4v*)(row + vb + 4);
          g[2] = *(const float4v*)(row + vb + 8);
          g[3] = *(const float4v*)(row + vb + 48);
          g[4] = *(const float4v*)(row + vb + 52);
          g[5] = *(const float4v*)(row + vb + 56);
        }
        float r0[12], r1[12];
        #pragma unroll
        for (int q = 0; q < 3; ++q)
          #pragma unroll
          for (int j = 0; j < 4; ++j) { r0[q*4+j] = g[q][j]; r1[q*4+j] = g[3+q][j]; }
        const int ln = (nd & 15) + 16 * w;
        #pragma unroll
        for (int x = 0; x < 3; ++x) {
          short8 h8, l8;
          #pragma unroll
          for (int j = 0; j < 4; ++j) {
            float v0 = r0[3 * j + x];
            unsigned short hb = f2bf(v0);
            h8[j] = (short)hb; l8[j] = (short)f2bf(v0 - bf2f(hb));
            float v1 = r1[3 * j + x];
            unsigned short hb2 = f2bf(v1);
            h8[4 + j] = (short)hb2; l8[4 + j] = (short)f2bf(v1 - bf2f(hb2));
          }
          const int rb = 4 + x * 4 + (nd >> 4);
          *(short8*)&Ah[rb][ln][0] = h8;
          *(short8*)&Al[rb][ln][0] = l8;
        }
      }
    }
    __syncthreads();
    // ---- compute: split-bf16 triple MFMA; B fragments straight from global (L2) ----
    {
      const int rb0 = wid * 4;
      const char* bh_base = bp_h + (size_t)c * CHUNK_SZ + (size_t)lane * 16;
      const char* bl_base = bp_l + (size_t)c * CHUNK_SZ + (size_t)lane * 16;
      short8 ah[4], al[4];
      #pragma unroll
      for (int i = 0; i < 4; ++i) {
        ah[i] = *(const short8*)&Ah[rb0 + i][lane][0];
        al[i] = *(const short8*)&Al[rb0 + i][lane][0];
      }
      #pragma unroll
      for (int nbv = 0; nbv < 8; ++nbv) {
        short8 bh = *(const short8*)(bh_base + nbv * 1024);
        short8 bl = *(const short8*)(bl_base + nbv * 1024);
        #pragma unroll
        for (int i = 0; i < 4; ++i) {
          acc[i][nbv] = MFMA_BF16(ah[i], bh, acc[i][nbv]);
          acc[i][nbv] = MFMA_BF16(al[i], bh, acc[i][nbv]);
          acc[i][nbv] = MFMA_BF16(ah[i], bl, acc[i][nbv]);
        }
      }
    }
  }

  // ---- epilogue: C/D layout col=lane&15, row=(lane>>4)*4+r ----
  const int rloc = (lane >> 4) * 4;
  const int cloc = lane & 15;
  if (wid == 0) {
    #pragma unroll
    for (int i = 0; i < 4; ++i)
      #pragma unroll
      for (int r = 0; r < 4; ++r) {
        const int node = i * 16 + rloc + r;
        if (node < nn) {
          float* orow = out + (size_t)nidx[node] * DIM;
          #pragma unroll
          for (int nbv = 0; nbv < 8; ++nbv)
            orow[nbv * 16 + cloc] = acc[i][nbv][r];
        }
      }
  } else {
    const int x = wid - 1;
    #pragma unroll
    for (int i = 0; i < 4; ++i)
      #pragma unroll
      for (int r = 0; r < 4; ++r) {
        const int node = i * 16 + rloc + r;
        if (node < nn) {
          float* orow = out + (size_t)nidx[node] * DIM + 128 + x;
          #pragma unroll
          for (int nbv = 0; nbv < 8; ++nbv)
            orow[(nbv * 16 + cloc) * 3] = acc[i][nbv][r];
        }
      }
  }
}

// ---------------- fallback: direct fp32 compute, no workspace needed ----------------
__global__ __launch_bounds__(512) void k_direct(const float* __restrict__ m_i,
                                                const float* __restrict__ feats,
                                                const float* __restrict__ attrs,
                                                const float* __restrict__ Wl0,
                                                const float* __restrict__ Wl1,
                                                const float* __restrict__ Wt0,
                                                const float* __restrict__ Wt1,
                                                float* __restrict__ out, int N) {
  __shared__ float mrow[512], frow[512];
  __shared__ int sa;
  const int n = blockIdx.x;
  const int t = threadIdx.x;
  mrow[t] = m_i[(size_t)n * DIM + t];
  frow[t] = feats[(size_t)n * DIM + t];
  if (t == 0) {
    int a = 0;
    for (int j = 1; j < NA; ++j) if (attrs[n * NA + j] > 0.5f) a = j;
    sa = a;
  }
  __syncthreads();
  const int a = sa;
  if (t < 128) {
    float s1 = 0.f, s2 = 0.f;
    for (int k = 0; k < 128; ++k) {
      s1 = fmaf(mrow[k], Wl0[k * 128 + t], s1);
      s2 = fmaf(frow[k], Wt0[(size_t)k * (NA * 128) + a * 128 + t], s2);
    }
    out[(size_t)n * DIM + t] = LIN_SCALE * s1 + TP_SCALE * s2;
  } else {
    const int i = t - 128, o = i / 3, x = i % 3;
    float s1 = 0.f, s2 = 0.f;
    for (int k = 0; k < 128; ++k) {
      float mv = mrow[128 + 3 * k + x], fv = frow[128 + 3 * k + x];
      s1 = fmaf(mv, Wl1[k * 128 + o], s1);
      s2 = fmaf(fv, Wt1[(size_t)k * (NA * 128) + a * 128 + o], s2);
    }
    out[(size_t)n * DIM + t] = LIN_SCALE * s1 + TP_SCALE * s2;
  }
}

extern "C" void kernel_launch(void* const* d_in, const int* in_sizes, int n_in,
                              void* d_out, int out_size, void* d_ws, size_t ws_size,
                              hipStream_t stream) {
  const float* m_i   = (const float*)d_in[0];
  const float* nf    = (const float*)d_in[1];
  const float* attrs = (const float*)d_in[2];
  const float* Wl0   = (const float*)d_in[3];
  const float* Wl1   = (const float*)d_in[4];
  const float* Wt0   = (const float*)d_in[5];
  const float* Wt1   = (const float*)d_in[6];
  float* out = (float*)d_out;
  const int N = in_sizes[0] / DIM;

  const size_t idxOff = (256 + (size_t)N * 4 + 255) & ~(size_t)255;
  const size_t need   = idxOff + 4 * (size_t)PLANE_SZ;
  if (ws_size < need) {
    // not enough scratch for the MFMA path — guaranteed-correct direct kernel
    k_direct<<<N, 512, 0, stream>>>(m_i, nf, attrs, Wl0, Wl1, Wt0, Wt1, out, N);
    return;
  }

  int*  wsI = (int*)d_ws;
  char* wb  = (char*)d_ws + idxOff;

  const int nb1 = (N + 255) / 256;
  k_zero<<<1, 64, 0, stream>>>(wsI);
  k_count<<<nb1, 256, 0, stream>>>(attrs, wsI, N);
  k_scan<<<1, 64, 0, stream>>>(wsI);
  k_scatter<<<nb1, 256, 0, stream>>>(attrs, wsI, N);
  k_prep<<<320, 256, 0, stream>>>(Wl0, Wl1, Wt0, Wt1, wb);
  dim3 g((N + 63) / 64, NA);
  k_gemm<<<g, 256, 0, stream>>>(m_i, nf, wsI, wb, out);
}

// Round 3
// 526.578 us; speedup vs baseline: 1.0697x; 1.0697x over previous
//
#include <hip/hip_runtime.h>
#include <stdint.h>

#define NA 10
#define DIM 512
#define LIN_SCALE 0.08838834764831845f   // 1/sqrt(128)
#define TP_SCALE  0.027950849718747374f  // 1/sqrt(1280)

// f16 B-plane: [type][a][c][nb][lane][8 f16] -> 10*8*8*64*16B per type
#define PLANE_SZ 655360

typedef __attribute__((ext_vector_type(8))) _Float16 half8;
typedef __attribute__((ext_vector_type(4))) _Float16 half4;
typedef __attribute__((ext_vector_type(4))) float f32x4;
typedef __attribute__((ext_vector_type(4))) float float4v;

#define MFMA_F16(A, B, C) __builtin_amdgcn_mfma_f32_16x16x32_f16((A), (B), (C), 0, 0, 0)

// ---------------- bucketing ----------------
// ws int layout: [0..15] cnt, [16..31] offs, [32..47] cursor, [64..] idx[N]
__global__ void k_zero(int* wsI) {
  if (threadIdx.x < 48) wsI[threadIdx.x] = 0;
}

__global__ __launch_bounds__(256) void k_count(const float* __restrict__ attrs,
                                               int* wsI, int N) {
  __shared__ int h[16];
  int t = threadIdx.x;
  int n = blockIdx.x * 256 + t;
  if (t < 16) h[t] = 0;
  __syncthreads();
  if (n < N) {
    int a = 0;
    #pragma unroll
    for (int j = 1; j < NA; ++j) if (attrs[n * NA + j] > 0.5f) a = j;
    atomicAdd(&h[a], 1);
  }
  __syncthreads();
  if (t < NA && h[t] > 0) atomicAdd(&wsI[t], h[t]);
}

__global__ void k_scan(int* wsI) {
  if (threadIdx.x == 0) {
    int run = 0;
    for (int a = 0; a < NA; ++a) {
      wsI[16 + a] = run;
      wsI[32 + a] = run;
      run += wsI[a];
    }
  }
}

__global__ __launch_bounds__(256) void k_scatter(const float* __restrict__ attrs,
                                                 int* wsI, int N) {
  __shared__ int h[16], base[16], c2[16];
  int t = threadIdx.x;
  int n = blockIdx.x * 256 + t;
  if (t < 16) { h[t] = 0; c2[t] = 0; }
  __syncthreads();
  int a = 0;
  if (n < N) {
    #pragma unroll
    for (int j = 1; j < NA; ++j) if (attrs[n * NA + j] > 0.5f) a = j;
    atomicAdd(&h[a], 1);
  }
  __syncthreads();
  if (t < NA && h[t] > 0) base[t] = atomicAdd(&wsI[32 + t], h[t]);
  __syncthreads();
  if (n < N) {
    int r = atomicAdd(&c2[a], 1);
    wsI[64 + base[a] + r] = n;
  }
}

// ---------------- weight prep: scale-folded f16 MFMA fragments ----------------
// fragment k-map (16x16x32): k = 4*(lane>>4) + (e&3) + 16*(e>>2); n = nb*16 + (lane&15)
__global__ __launch_bounds__(256) void k_prep(const float* __restrict__ Wl0,
                                              const float* __restrict__ Wl1,
                                              const float* __restrict__ Wt0,
                                              const float* __restrict__ Wt1,
                                              char* __restrict__ wb) {
  int gid = blockIdx.x * 256 + threadIdx.x;  // 2type*10a*8c*8nb*64lane = 81920
  int l  = gid & 63;
  int nb = (gid >> 6) & 7;
  int c  = (gid >> 9) & 7;
  int ac = gid >> 12;        // 0..19
  int a  = ac % NA;
  int type = ac / NA;
  const float* Wl = type ? Wl1 : Wl0;
  const float* Wt = type ? Wt1 : Wt0;
  half8 h;
  #pragma unroll
  for (int e = 0; e < 8; ++e) {
    int k = c * 32 + (e >> 2) * 16 + (l >> 4) * 4 + (e & 3);
    int n = nb * 16 + (l & 15);
    float w = (k < 128) ? (LIN_SCALE * Wl[k * 128 + n])
                        : (TP_SCALE * Wt[(size_t)(k - 128) * (NA * 128) + a * 128 + n]);
    h[e] = (_Float16)w;
  }
  *(half8*)(wb + (size_t)type * PLANE_SZ +
            ((size_t)((a * 8 + c) * 8 + nb) * 64 + l) * 16) = h;
}

// ---------------- main GEMM ----------------
// 512 threads = 8 waves, 64 nodes/block of one bucket.
// waves 0-1: scalar rows (rb 0-3), nbv-half = w.  waves 2-7: vector channel
// x=(w-2)>>1, nbv-half = (w-2)&1, rb 4+4x..7+4x.
// A tile f16 double-buffered in LDS; B fragments from prepacked ws (L2-resident).
__global__ __launch_bounds__(512, 4) void k_gemm(const float* __restrict__ m_i,
                                                 const float* __restrict__ feats,
                                                 const int* __restrict__ wsI,
                                                 const char* __restrict__ wb,
                                                 float* __restrict__ out) {
  __shared__ __attribute__((aligned(16))) _Float16 A[2][16][64][8];  // 32 KB
  __shared__ int nidx[64];

  const int a  = blockIdx.y;
  const int t0 = blockIdx.x * 64;
  const int ca = wsI[a];
  if (t0 >= ca) return;
  const int nn = (ca - t0 < 64) ? (ca - t0) : 64;
  const int tid = threadIdx.x;
  if (tid < 64) nidx[tid] = (tid < nn) ? wsI[64 + wsI[16 + a] + t0 + tid] : 0;

  const int w    = tid >> 6;          // wave 0..7
  const int lane = tid & 63;
  const int nd   = tid >> 3;          // staging: node 0..63
  const int sub  = tid & 7;
  const int wq   = sub >> 1;          // k-quad 0..3
  const int hh   = sub & 1;           // fragment half (e0-3 / e4-7)
  const int ln   = (nd & 15) + 16 * wq;
  const int rbs  = nd >> 4;

  const bool scalarW = (w < 2);
  const int  xch = scalarW ? 0 : ((w - 2) >> 1);
  const int  nh  = scalarW ? w : ((w - 2) & 1);
  const int  rb0 = scalarW ? 0 : 4 + 4 * xch;
  const char* bbase = wb + (scalarW ? (size_t)0 : (size_t)PLANE_SZ) +
                      (size_t)a * 65536 + (size_t)nh * 4096 + (size_t)lane * 16;

  __syncthreads();  // nidx visible

  f32x4 acc[4][4];
  #pragma unroll
  for (int i = 0; i < 4; ++i)
    #pragma unroll
    for (int n4 = 0; n4 < 4; ++n4)
      acc[i][n4] = (f32x4){0.f, 0.f, 0.f, 0.f};

  // stage one k-chunk cs into LDS buffer pb
  auto stage = [&](int cs, int pb) {
    const float* src = (cs < 4) ? m_i : feats;
    const int cc = cs & 3;
    const float* row = src + (size_t)nidx[nd] * DIM;
    // scalar: k = cc*32 + 4wq + 16hh + j
    float4v s4 = *(const float4v*)(row + cc * 32 + 4 * wq + 16 * hh);
    // vector: 12 consecutive floats cover j=0..3 x channels 0..2
    const int vb = 128 + cc * 96 + 12 * wq + 48 * hh;
    float4v g0 = *(const float4v*)(row + vb);
    float4v g1 = *(const float4v*)(row + vb + 4);
    float4v g2 = *(const float4v*)(row + vb + 8);
    half4 sh;
    #pragma unroll
    for (int j = 0; j < 4; ++j) sh[j] = (_Float16)s4[j];
    *(half4*)&A[pb][rbs][ln][4 * hh] = sh;
    #pragma unroll
    for (int x = 0; x < 3; ++x) {
      half4 vh;
      #pragma unroll
      for (int j = 0; j < 4; ++j) {
        const int idx = 3 * j + x;
        float v = (idx < 4) ? g0[idx] : (idx < 8) ? g1[idx - 4] : g2[idx - 8];
        vh[j] = (_Float16)v;
      }
      *(half4*)&A[pb][4 + 4 * x + rbs][ln][4 * hh] = vh;
    }
  };

  stage(0, 0);
  __syncthreads();

  for (int c = 0; c < 8; ++c) {
    const int p = c & 1;
    // ---- compute chunk c ----
    {
      half8 afr[4];
      #pragma unroll
      for (int i = 0; i < 4; ++i)
        afr[i] = *(const half8*)&A[p][rb0 + i][lane][0];
      const char* bc = bbase + (size_t)c * 8192;
      half8 b0 = *(const half8*)(bc);
      half8 b1 = *(const half8*)(bc + 1024);
      #pragma unroll
      for (int i = 0; i < 4; ++i) acc[i][0] = MFMA_F16(afr[i], b0, acc[i][0]);
      b0 = *(const half8*)(bc + 2048);
      #pragma unroll
      for (int i = 0; i < 4; ++i) acc[i][1] = MFMA_F16(afr[i], b1, acc[i][1]);
      b1 = *(const half8*)(bc + 3072);
      #pragma unroll
      for (int i = 0; i < 4; ++i) acc[i][2] = MFMA_F16(afr[i], b0, acc[i][2]);
      #pragma unroll
      for (int i = 0; i < 4; ++i) acc[i][3] = MFMA_F16(afr[i], b1, acc[i][3]);
    }
    // ---- stage next chunk into other buffer ----
    if (c < 7) stage(c + 1, p ^ 1);
    __syncthreads();
  }

  // ---- epilogue: C/D layout col=lane&15, row=(lane>>4)*4+r ----
  const int rloc = (lane >> 4) * 4;
  const int cloc = lane & 15;
  if (scalarW) {
    #pragma unroll
    for (int i = 0; i < 4; ++i)
      #pragma unroll
      for (int r = 0; r < 4; ++r) {
        const int node = i * 16 + rloc + r;
        if (node < nn) {
          float* orow = out + (size_t)nidx[node] * DIM + nh * 64;
          #pragma unroll
          for (int n4 = 0; n4 < 4; ++n4)
            orow[n4 * 16 + cloc] = acc[i][n4][r];
        }
      }
  } else {
    #pragma unroll
    for (int i = 0; i < 4; ++i)
      #pragma unroll
      for (int r = 0; r < 4; ++r) {
        const int node = i * 16 + rloc + r;
        if (node < nn) {
          float* orow = out + (size_t)nidx[node] * DIM + 128 + xch;
          #pragma unroll
          for (int n4 = 0; n4 < 4; ++n4)
            orow[((nh * 4 + n4) * 16 + cloc) * 3] = acc[i][n4][r];
        }
      }
  }
}

// ---------------- fallback: direct fp32 compute, no workspace needed ----------------
__global__ __launch_bounds__(512) void k_direct(const float* __restrict__ m_i,
                                                const float* __restrict__ feats,
                                                const float* __restrict__ attrs,
                                                const float* __restrict__ Wl0,
                                                const float* __restrict__ Wl1,
                                                const float* __restrict__ Wt0,
                                                const float* __restrict__ Wt1,
                                                float* __restrict__ out, int N) {
  __shared__ float mrow[512], frow[512];
  __shared__ int sa;
  const int n = blockIdx.x;
  const int t = threadIdx.x;
  mrow[t] = m_i[(size_t)n * DIM + t];
  frow[t] = feats[(size_t)n * DIM + t];
  if (t == 0) {
    int a = 0;
    for (int j = 1; j < NA; ++j) if (attrs[n * NA + j] > 0.5f) a = j;
    sa = a;
  }
  __syncthreads();
  const int a = sa;
  if (t < 128) {
    float s1 = 0.f, s2 = 0.f;
    for (int k = 0; k < 128; ++k) {
      s1 = fmaf(mrow[k], Wl0[k * 128 + t], s1);
      s2 = fmaf(frow[k], Wt0[(size_t)k * (NA * 128) + a * 128 + t], s2);
    }
    out[(size_t)n * DIM + t] = LIN_SCALE * s1 + TP_SCALE * s2;
  } else {
    const int i = t - 128, o = i / 3, x = i % 3;
    float s1 = 0.f, s2 = 0.f;
    for (int k = 0; k < 128; ++k) {
      float mv = mrow[128 + 3 * k + x], fv = frow[128 + 3 * k + x];
      s1 = fmaf(mv, Wl1[k * 128 + o], s1);
      s2 = fmaf(fv, Wt1[(size_t)k * (NA * 128) + a * 128 + o], s2);
    }
    out[(size_t)n * DIM + t] = LIN_SCALE * s1 + TP_SCALE * s2;
  }
}

extern "C" void kernel_launch(void* const* d_in, const int* in_sizes, int n_in,
                              void* d_out, int out_size, void* d_ws, size_t ws_size,
                              hipStream_t stream) {
  const float* m_i   = (const float*)d_in[0];
  const float* nf    = (const float*)d_in[1];
  const float* attrs = (const float*)d_in[2];
  const float* Wl0   = (const float*)d_in[3];
  const float* Wl1   = (const float*)d_in[4];
  const float* Wt0   = (const float*)d_in[5];
  const float* Wt1   = (const float*)d_in[6];
  float* out = (float*)d_out;
  const int N = in_sizes[0] / DIM;

  const size_t idxOff = (256 + (size_t)N * 4 + 255) & ~(size_t)255;
  const size_t need   = idxOff + 2 * (size_t)PLANE_SZ;
  if (ws_size < need) {
    k_direct<<<N, 512, 0, stream>>>(m_i, nf, attrs, Wl0, Wl1, Wt0, Wt1, out, N);
    return;
  }

  int*  wsI = (int*)d_ws;
  char* wb  = (char*)d_ws + idxOff;

  const int nb1 = (N + 255) / 256;
  k_zero<<<1, 64, 0, stream>>>(wsI);
  k_count<<<nb1, 256, 0, stream>>>(attrs, wsI, N);
  k_scan<<<1, 64, 0, stream>>>(wsI);
  k_scatter<<<nb1, 256, 0, stream>>>(attrs, wsI, N);
  k_prep<<<320, 256, 0, stream>>>(Wl0, Wl1, Wt0, Wt1, wb);
  dim3 g((N + 63) / 64, NA);
  k_gemm<<<g, 512, 0, stream>>>(m_i, nf, wsI, wb, out);
}